// Round 5
// baseline (242.548 us; speedup 1.0000x reference)
//
#include <hip/hip_runtime.h>
#include <hip/hip_bf16.h>

#define NN 8
#define TT 192
#define HH 1024
#define DD 128
#define TPP 48
#define EE 16384
#define NEDGE (EE + HH)      // 17408
#define BB (NN * TPP)        // 384
#define NOUT (NN * TT * DD)  // 196608

typedef short bf16x8 __attribute__((ext_vector_type(8)));
typedef float f32x4 __attribute__((ext_vector_type(4)));

__device__ __forceinline__ float bf2f(__hip_bfloat16 h) { return __bfloat162float(h); }

// ---------------- setup: degree, inv, W1/W2 pre-swizzle, tw transpose ----------------
__global__ void k_setup(const int* __restrict__ edges, int* __restrict__ degE,
                        const int* __restrict__ node_split, int* __restrict__ inv,
                        const float* __restrict__ W1, __hip_bfloat16* __restrict__ w1sw,
                        const float* __restrict__ W2, __hip_bfloat16* __restrict__ w2sw,
                        const float* __restrict__ tw, float* __restrict__ twT) {
  int i = blockIdx.x * 256 + threadIdx.x;  // grid 256*256 = 65536
  if (i < EE) atomicAdd(&degE[edges[2 * i + 1]], 1);
  if (i < HH) inv[node_split[i]] = i;
  if (i < DD * DD) {
    int n = i >> 7, k = i & 127;  // B[n][k] = W[k][n], swizzled 16B granules
    int dstb = n * 256 + ((((k >> 3)) ^ (n & 7)) * 16) + (k & 7) * 2;
    w1sw[dstb >> 1] = __float2bfloat16(W1[k * DD + n]);
    w2sw[dstb >> 1] = __float2bfloat16(W2[k * DD + n]);
  }
  {
    int o = i >> 9, ck = i & 511;  // i < 65536 always
    twT[ck * DD + o] = tw[i];
  }
}

// shfl-based scan: row_ptr = exclusive prefix of (deg+1)
__global__ __launch_bounds__(1024) void k_scan(const int* __restrict__ degE,
                                               int* __restrict__ row_ptr) {
  int t = threadIdx.x, lane = t & 63, wid = t >> 6;
  int v = degE[t] + 1;
#pragma unroll
  for (int off = 1; off < 64; off <<= 1) {
    int u = __shfl_up(v, off, 64);
    if (lane >= off) v += u;
  }
  __shared__ int wsum[16];
  if (lane == 63) wsum[wid] = v;
  __syncthreads();
  if (t < 64) {
    int s = (lane < 16) ? wsum[lane] : 0;
#pragma unroll
    for (int off = 1; off < 16; off <<= 1) {
      int u = __shfl_up(s, off, 64);
      if (lane >= off) s += u;
    }
    if (lane < 16) wsum[lane] = s;
  }
  __syncthreads();
  int base = wid ? wsum[wid - 1] : 0;
  row_ptr[t + 1] = base + v;
  if (t == 0) row_ptr[0] = 0;
}

__global__ void k_scatter(const int* __restrict__ edges, const int* __restrict__ degE,
                          const int* __restrict__ row_ptr, const int* __restrict__ inv,
                          int* __restrict__ fill, int* __restrict__ csr_src,
                          float* __restrict__ csr_coef, float* __restrict__ Q) {
  int e = blockIdx.x * 256 + threadIdx.x;
  if (e >= NEDGE) return;
  int s, dt;
  if (e < EE) { s = edges[2 * e]; dt = edges[2 * e + 1]; }
  else        { s = dt = e - EE; }
  float ds = (float)(degE[s] + 1);
  float dd = (float)(degE[dt] + 1);
  float cf = rsqrtf(ds * dd);
  int pos = atomicAdd(&fill[dt], 1);
  int at = row_ptr[dt] + pos;
  csr_src[at] = s;
  csr_coef[at] = cf;
  int g = inv[dt] >> 8;
  atomicAdd(&Q[g * HH + s], cf * (1.0f / 256.0f));
}

// ---------------- time embedding: coalesced twT reads ----------------
__global__ __launch_bounds__(256) void k_time(const int* __restrict__ xm,
                                              const float* __restrict__ hour_emb,
                                              const float* __restrict__ wday_emb,
                                              const float* __restrict__ twT,
                                              const float* __restrict__ tcb,
                                              float* __restrict__ out) {
  int tid = threadIdx.x;
  int half = tid >> 7, o = tid & 127;
  int b = blockIdx.x * 2 + half;
  int n = b / TPP, tp = b % TPP;
  __shared__ float sL[2][512];
  for (int k = 0; k < 4; ++k) {
    int t = tp * 4 + k;
    int wd = xm[(n * TT + t) * 2 + 0];
    int hr = xm[(n * TT + t) * 2 + 1];
    sL[half][o * 4 + k] = hour_emb[hr * DD + o] + wday_emb[wd * DD + o];
  }
  __syncthreads();
  float a0 = tcb[o], a1 = 0.f, a2 = 0.f, a3 = 0.f;
  for (int j = 0; j < 512; j += 4) {
    a0 = fmaf(sL[half][j + 0], twT[(j + 0) * DD + o], a0);
    a1 = fmaf(sL[half][j + 1], twT[(j + 1) * DD + o], a1);
    a2 = fmaf(sL[half][j + 2], twT[(j + 2) * DD + o], a2);
    a3 = fmaf(sL[half][j + 3], twT[(j + 3) * DD + o], a3);
  }
  float acc = (a0 + a1) + (a2 + a3);
  size_t base = (size_t)NOUT + ((size_t)n * TT + tp * 4) * DD + o;
  out[base] = acc;
  out[base + DD] = acc;
  out[base + 2 * DD] = acc;
  out[base + 3 * DD] = acc;
}

// ---------------- fused gather + conv-expand + MFMA GEMM, spill-free ----------------
// Block = (quarter q, batch b): 256 h-rows, four 64x128x128 chunk GEMMs.
// LDS: W1 32K + Gr 16K + xbar 5K + yL 2K = 55 KB. acc[8]=32 regs, per-chunk reduce.
__global__ __launch_bounds__(256, 2) void k_gemm(
    const float* __restrict__ x, const float* __restrict__ tcw,
    const float* __restrict__ tcb, const __hip_bfloat16* __restrict__ w1sw,
    const float* __restrict__ bias1, const int* __restrict__ row_ptr,
    const int* __restrict__ csr_src, const float* __restrict__ csr_coef,
    const float* __restrict__ Q, __hip_bfloat16* __restrict__ ypart) {
  __shared__ __align__(16) char Wr[32768];
  __shared__ __align__(16) char Gr[16384];
  __shared__ float xbarL[256 * 5];
  __shared__ float yL[512];
  int tid = threadIdx.x;
  int q = blockIdx.x, b = blockIdx.y;
  int h0 = q * 256;
  int n_ = b / TPP, tp = b % TPP;

  // stage W1 (pre-swizzled, linear copy) and x-patch (fp32 -> bf16 [s][k]) into Gr
  {
    const uint4* ws = (const uint4*)w1sw;
    uint4* wd = (uint4*)Wr;
    for (int i = tid; i < 2048; i += 256) wd[i] = ws[i];
    const float* xb = x + ((size_t)n_ * TT + tp * 4) * HH;
    __hip_bfloat16* xp = (__hip_bfloat16*)Gr;
    for (int i = tid; i < 4096; i += 256) {
      int s = i & 1023, k = i >> 10;  // i = k*1024+s, coalesced read
      xp[s * 4 + k] = __float2bfloat16(xb[i]);
    }
    yL[tid] = 0.f;
    yL[tid + 256] = 0.f;
  }
  // per-thread constants
  int dp = tid & 63, d0 = dp * 2;
  float twa0 = tcw[d0 * 4 + 0], twa1 = tcw[d0 * 4 + 1];
  float twa2 = tcw[d0 * 4 + 2], twa3 = tcw[d0 * 4 + 3];
  float twb0 = tcw[d0 * 4 + 4], twb1 = tcw[d0 * 4 + 5];
  float twb2 = tcw[d0 * 4 + 6], twb3 = tcw[d0 * 4 + 7];
  float tba = tcb[d0], tbb = tcb[d0 + 1];
  int lane = tid & 63, w = tid >> 6;
  int colq = lane & 15, quad = lane >> 4;
  float bias[8];
#pragma unroll
  for (int jn = 0; jn < 8; ++jn) bias[jn] = bias1[jn * 16 + colq];
  __syncthreads();

  // phase A: 1 thread per row; xbar[r][0..3]=sum cf*x4, [4]=sum cf
  {
    int h = h0 + tid;
    int j0 = row_ptr[h], j1 = row_ptr[h + 1];
    float a0 = 0.f, a1 = 0.f, a2 = 0.f, a3 = 0.f, cs = 0.f;
    const uint2* xu = (const uint2*)Gr;
    for (int j = j0; j < j1; ++j) {
      int s = csr_src[j];
      float cf = csr_coef[j];
      uint2 u = xu[s];
      union { unsigned i; float f; } t0, t1, t2, t3;
      t0.i = u.x << 16;
      t1.i = u.x & 0xffff0000u;
      t2.i = u.y << 16;
      t3.i = u.y & 0xffff0000u;
      a0 = fmaf(cf, t0.f, a0);
      a1 = fmaf(cf, t1.f, a1);
      a2 = fmaf(cf, t2.f, a2);
      a3 = fmaf(cf, t3.f, a3);
      cs += cf;
    }
    xbarL[tid * 5 + 0] = a0;
    xbarL[tid * 5 + 1] = a1;
    xbarL[tid * 5 + 2] = a2;
    xbarL[tid * 5 + 3] = a3;
    xbarL[tid * 5 + 4] = cs;
  }
  __syncthreads();

  int ggA = dp >> 2;
  for (int ch = 0; ch < 4; ++ch) {
    if (ch) __syncthreads();  // prior chunk's Gr reads complete
    // A2: agg[row][d] for 64 rows -> bf16 swizzled into Gr
#pragma unroll 4
    for (int it = 0; it < 16; ++it) {
      int row = it * 4 + (tid >> 6);  // wave-uniform
      const float* xr = &xbarL[(ch * 64 + row) * 5];
      float x0 = xr[0], x1 = xr[1], x2 = xr[2], x3 = xr[3], xc = xr[4];
      float v0 = xc * tba;
      v0 = fmaf(x0, twa0, v0); v0 = fmaf(x1, twa1, v0);
      v0 = fmaf(x2, twa2, v0); v0 = fmaf(x3, twa3, v0);
      float v1 = xc * tbb;
      v1 = fmaf(x0, twb0, v1); v1 = fmaf(x1, twb1, v1);
      v1 = fmaf(x2, twb2, v1); v1 = fmaf(x3, twb3, v1);
      union { __hip_bfloat16 h[2]; unsigned u; } pk;
      pk.h[0] = __float2bfloat16(v0);
      pk.h[1] = __float2bfloat16(v1);
      *(unsigned*)(Gr + row * 256 + ((ggA ^ (row & 7)) * 16) + (dp & 3) * 4) = pk.u;
    }
    // Q prefetch (overlaps with GEMM)
    int rb = h0 + ch * 64 + w * 16 + quad * 4;
    float qg[4][4];
#pragma unroll
    for (int g = 0; g < 4; ++g)
#pragma unroll
      for (int reg = 0; reg < 4; ++reg) qg[g][reg] = Q[g * HH + rb + reg];
    __syncthreads();

    // GEMM 64x128x128: wave w -> m-tile w, n-tiles 0..7
    f32x4 acc[8];
#pragma unroll
    for (int jn = 0; jn < 8; ++jn) acc[jn] = (f32x4){0.f, 0.f, 0.f, 0.f};
    int arow = w * 16 + colq;
#pragma unroll
    for (int kc = 0; kc < 4; ++kc) {
      bf16x8 af = *(const bf16x8*)(Gr + arow * 256 + (((kc * 4 + quad) ^ (arow & 7)) * 16));
#pragma unroll
      for (int jn = 0; jn < 8; ++jn) {
        int nr = jn * 16 + colq;
        bf16x8 bf = *(const bf16x8*)(Wr + nr * 256 + (((kc * 4 + quad) ^ (nr & 7)) * 16));
        acc[jn] = __builtin_amdgcn_mfma_f32_16x16x32_bf16(af, bf, acc[jn], 0, 0, 0);
      }
    }

    // epilogue: relu(+b1), Q-weight, quad shfl-reduce, 8 LDS atomics/thread
#pragma unroll
    for (int jn = 0; jn < 8; ++jn) {
      float bo = bias[jn];
      float v0 = fmaxf(acc[jn][0] + bo, 0.f);
      float v1 = fmaxf(acc[jn][1] + bo, 0.f);
      float v2 = fmaxf(acc[jn][2] + bo, 0.f);
      float v3 = fmaxf(acc[jn][3] + bo, 0.f);
      float r[4];
#pragma unroll
      for (int g = 0; g < 4; ++g) {
        float pg = qg[g][0] * v0 + qg[g][1] * v1;
        pg = fmaf(qg[g][2], v2, pg);
        pg = fmaf(qg[g][3], v3, pg);
        pg += __shfl_xor(pg, 16, 64);
        pg += __shfl_xor(pg, 32, 64);
        r[g] = pg;
      }
      float vq = (quad == 0) ? r[0] : (quad == 1) ? r[1] : (quad == 2) ? r[2] : r[3];
      atomicAdd(&yL[quad * DD + jn * 16 + colq], vq);
    }
  }
  __syncthreads();
  __hip_bfloat16* yp = ypart + ((size_t)q * BB + b) * 512;
  yp[tid] = __float2bfloat16(yL[tid]);
  yp[tid + 256] = __float2bfloat16(yL[tid + 256]);
}

// ---------------- epilogue GEMM: out0 = (sum_q ypart) @ W2 + b2 + time ----------------
// 24 blocks x 64 rows of Y (row = b*4+g). LDS: W2 32K + A 16K.
__global__ __launch_bounds__(256, 2) void k_out(const __hip_bfloat16* __restrict__ ypart,
                                                const __hip_bfloat16* __restrict__ w2sw,
                                                const float* __restrict__ b2,
                                                float* __restrict__ out) {
  __shared__ __align__(16) char Wr[32768];
  __shared__ __align__(16) char Gr[16384];
  int tid = threadIdx.x;
  int m0 = blockIdx.x * 64;
  {
    const uint4* ws = (const uint4*)w2sw;
    uint4* wd = (uint4*)Wr;
    for (int i = tid; i < 2048; i += 256) wd[i] = ws[i];
  }
  // build A: 64 rows x 128 k (sum 4 quarters), bf16 pairs, swizzled
  const unsigned* yu = (const unsigned*)ypart;
#pragma unroll 4
  for (int it = 0; it < 16; ++it) {
    int idx = it * 256 + tid;
    int row = idx >> 6, kp = idx & 63;
    int m = m0 + row;
    int base = (m >> 2) * 256 + (m & 3) * 64 + kp;  // uint index within a quarter
    float s0 = 0.f, s1 = 0.f;
#pragma unroll
    for (int qq = 0; qq < 4; ++qq) {
      unsigned u = yu[qq * (BB * 256) + base];
      union { unsigned i; float f; } t0, t1;
      t0.i = u << 16;
      t1.i = u & 0xffff0000u;
      s0 += t0.f;
      s1 += t1.f;
    }
    union { __hip_bfloat16 h[2]; unsigned u; } pk;
    pk.h[0] = __float2bfloat16(s0);
    pk.h[1] = __float2bfloat16(s1);
    *(unsigned*)(Gr + row * 256 + (((kp >> 2) ^ (row & 7)) * 16) + (kp & 3) * 4) = pk.u;
  }
  int lane = tid & 63, w = tid >> 6;
  int colq = lane & 15, quad = lane >> 4;
  float bo[8];
#pragma unroll
  for (int jn = 0; jn < 8; ++jn) bo[jn] = b2[jn * 16 + colq];
  __syncthreads();

  f32x4 acc[8];
#pragma unroll
  for (int jn = 0; jn < 8; ++jn) acc[jn] = (f32x4){0.f, 0.f, 0.f, 0.f};
  int arow = w * 16 + colq;
#pragma unroll
  for (int kc = 0; kc < 4; ++kc) {
    bf16x8 af = *(const bf16x8*)(Gr + arow * 256 + (((kc * 4 + quad) ^ (arow & 7)) * 16));
#pragma unroll
    for (int jn = 0; jn < 8; ++jn) {
      int nr = jn * 16 + colq;
      bf16x8 bf = *(const bf16x8*)(Wr + nr * 256 + (((kc * 4 + quad) ^ (nr & 7)) * 16));
      acc[jn] = __builtin_amdgcn_mfma_f32_16x16x32_bf16(af, bf, acc[jn], 0, 0, 0);
    }
  }
#pragma unroll
  for (int reg = 0; reg < 4; ++reg) {
    int m = m0 + w * 16 + quad * 4 + reg;
    int b = m >> 2, g = m & 3;
    int n_ = b / TPP, tp = b % TPP;
    size_t rb = ((size_t)(n_ * TT + tp * 4 + g)) * DD;
#pragma unroll
    for (int jn = 0; jn < 8; ++jn) {
      int o = jn * 16 + colq;
      out[rb + o] = acc[jn][reg] + bo[jn] + out[(size_t)NOUT + rb + o];
    }
  }
}

extern "C" void kernel_launch(void* const* d_in, const int* in_sizes, int n_in,
                              void* d_out, int out_size, void* d_ws, size_t ws_size,
                              hipStream_t stream) {
  const float* x = (const float*)d_in[0];
  const int* xm = (const int*)d_in[1];
  const int* edges = (const int*)d_in[2];
  const int* node_split = (const int*)d_in[3];
  const float* hour_emb = (const float*)d_in[4];
  const float* wday_emb = (const float*)d_in[5];
  const float* timeconv_w = (const float*)d_in[6];
  const float* timeconv_b = (const float*)d_in[7];
  const float* tcw = (const float*)d_in[8];
  const float* tcb = (const float*)d_in[9];
  const float* W1 = (const float*)d_in[10];
  const float* b1 = (const float*)d_in[11];
  const float* W2 = (const float*)d_in[12];
  const float* b2 = (const float*)d_in[13];
  float* out = (float*)d_out;

  char* w = (char*)d_ws;
  int* degE = (int*)(w + 0);                 //    4096 B (zeroed)
  int* fill = (int*)(w + 4096);              //    4096 B (zeroed)
  float* Q = (float*)(w + 8192);             //   16384 B (zeroed)
  size_t zbytes = 24576;
  int* row_ptr = (int*)(w + 24576);          //    4352 B
  int* inv = (int*)(w + 28928);              //    4096 B
  int* csr_src = (int*)(w + 33024);          //   69632 B
  float* csr_coef = (float*)(w + 102656);    //   69632 B
  __hip_bfloat16* w1sw = (__hip_bfloat16*)(w + 172288);   //  32768 B
  __hip_bfloat16* w2sw = (__hip_bfloat16*)(w + 205056);   //  32768 B
  float* twT = (float*)(w + 237824);                      // 262144 B
  __hip_bfloat16* ypart = (__hip_bfloat16*)(w + 499968);  // 1572864 B (end ~2.07 MB)

  hipMemsetAsync(d_ws, 0, zbytes, stream);
  k_setup<<<256, 256, 0, stream>>>(edges, degE, node_split, inv, W1, w1sw, W2, w2sw,
                                   timeconv_w, twT);
  k_scan<<<1, 1024, 0, stream>>>(degE, row_ptr);
  k_scatter<<<68, 256, 0, stream>>>(edges, degE, row_ptr, inv, fill, csr_src, csr_coef, Q);
  k_time<<<BB / 2, 256, 0, stream>>>(xm, hour_emb, wday_emb, twT, timeconv_b, out);
  dim3 gmain(4, BB);
  k_gemm<<<gmain, 256, 0, stream>>>(x, tcw, tcb, w1sw, b1, row_ptr, csr_src, csr_coef, Q,
                                    ypart);
  k_out<<<24, 256, 0, stream>>>(ypart, w2sw, b2, out);
}

// Round 6
// 153.986 us; speedup vs baseline: 1.5751x; 1.5751x over previous
//
#include <hip/hip_runtime.h>
#include <hip/hip_bf16.h>

#define NN 8
#define TT 192
#define HH 1024
#define DD 128
#define TPP 48
#define EE 16384
#define NEDGE (EE + HH)      // 17408
#define BB (NN * TPP)        // 384
#define NOUT (NN * TT * DD)  // 196608

typedef short bf16x8 __attribute__((ext_vector_type(8)));
typedef float f32x4 __attribute__((ext_vector_type(4)));

__device__ __forceinline__ float bf2f(__hip_bfloat16 h) { return __bfloat162float(h); }
__device__ __forceinline__ float us2f(unsigned short u) {
  union { unsigned i; float f; } t;
  t.i = ((unsigned)u) << 16;
  return t.f;
}

// ---------------- setup: deg atomics, inv, twT, zero-fill, x transpose ----------------
// grid 384 x 256. Blocks tile the 64x64 transpose of x (1536 x 1024 -> Xall bf16).
__global__ __launch_bounds__(256) void k_setup(
    const int* __restrict__ edges, int* __restrict__ degE,
    const int* __restrict__ node_split, int* __restrict__ inv,
    const float* __restrict__ tw, float* __restrict__ twT,
    float* __restrict__ zbuf,  // fill|cs|QT region, 6144 floats
    const float* __restrict__ x, __hip_bfloat16* __restrict__ Xall) {
  __shared__ float tile[64][65];
  int tid = threadIdx.x, bid = blockIdx.x;
  int i = bid * 256 + tid;
  if (i < EE) atomicAdd(&degE[edges[2 * i + 1]], 1);
  if (i < HH) inv[node_split[i]] = i;
  if (i < 65536) twT[(i & 511) * DD + (i >> 9)] = tw[i];
  if (i < 6144) zbuf[i] = 0.f;

  int tt = bid % 24, st = bid / 24;  // t-tile, s-tile
  int t0 = tt * 64, s0 = st * 64;
  int sl = tid & 63, r4 = tid >> 6;
#pragma unroll 4
  for (int ii = 0; ii < 16; ++ii) {
    int tl = ii * 4 + r4;
    tile[tl][sl] = x[(size_t)(t0 + tl) * HH + s0 + sl];
  }
  __syncthreads();
#pragma unroll 4
  for (int ii = 0; ii < 16; ++ii) {
    int sl2 = ii * 4 + r4;
    Xall[(size_t)(s0 + sl2) * 1536 + t0 + sl] = __float2bfloat16(tile[sl][sl2]);
  }
}

// ---------------- 1-block: scan + CW = Conv@W1 + W2 swizzle ----------------
__global__ __launch_bounds__(1024) void k_scan(const int* __restrict__ degE,
                                               int* __restrict__ row_ptr,
                                               const float* __restrict__ tcw,
                                               const float* __restrict__ tcb,
                                               const float* __restrict__ W1,
                                               float* __restrict__ CW,
                                               const float* __restrict__ W2,
                                               __hip_bfloat16* __restrict__ w2sw) {
  int t = threadIdx.x, lane = t & 63, wid = t >> 6;
  int v = degE[t] + 1;  // +1 self loop
#pragma unroll
  for (int off = 1; off < 64; off <<= 1) {
    int u = __shfl_up(v, off, 64);
    if (lane >= off) v += u;
  }
  __shared__ int wsum[16];
  if (lane == 63) wsum[wid] = v;
  __syncthreads();
  if (t < 64) {
    int s = (lane < 16) ? wsum[lane] : 0;
#pragma unroll
    for (int off = 1; off < 16; off <<= 1) {
      int u = __shfl_up(s, off, 64);
      if (lane >= off) s += u;
    }
    if (lane < 16) wsum[lane] = s;
  }
  __syncthreads();
  int base = wid ? wsum[wid - 1] : 0;
  row_ptr[t + 1] = base + v;
  if (t == 0) row_ptr[0] = 0;

  // CW[j][o] = sum_d Conv[j][d] * W1[d][o];  Conv[j<4][d]=tcw[d*4+j], Conv[4][d]=tcb[d]
  if (t < 640) {
    int j = t >> 7, o = t & 127;
    float acc = 0.f;
    if (j < 4)
      for (int d = 0; d < DD; ++d) acc = fmaf(tcw[d * 4 + j], W1[d * DD + o], acc);
    else
      for (int d = 0; d < DD; ++d) acc = fmaf(tcb[d], W1[d * DD + o], acc);
    CW[j * DD + o] = acc;
  }
  // W2 swizzled bf16 [n][k] for k_out MFMA B operand
#pragma unroll 4
  for (int u = 0; u < 16; ++u) {
    int i = t * 16 + u;
    int n = i >> 7, k = i & 127;
    int dstb = n * 256 + (((k >> 3) ^ (n & 7)) * 16) + (k & 7) * 2;
    w2sw[dstb >> 1] = __float2bfloat16(W2[k * DD + n]);
  }
}

// ---------------- scatter: CSR + cs row-sums + QT (group-mean fold) ----------------
__global__ void k_scatter(const int* __restrict__ edges, const int* __restrict__ degE,
                          const int* __restrict__ row_ptr, const int* __restrict__ inv,
                          int* __restrict__ fill, int* __restrict__ csr_src,
                          float* __restrict__ csr_coef, float* __restrict__ csum,
                          float* __restrict__ QT) {
  int e = blockIdx.x * 256 + threadIdx.x;
  if (e >= NEDGE) return;
  int s, dt;
  if (e < EE) { s = edges[2 * e]; dt = edges[2 * e + 1]; }
  else        { s = dt = e - EE; }
  float ds = (float)(degE[s] + 1);
  float dd = (float)(degE[dt] + 1);
  float cf = rsqrtf(ds * dd);
  int pos = atomicAdd(&fill[dt], 1);
  int at = row_ptr[dt] + pos;
  csr_src[at] = s;
  csr_coef[at] = cf;
  atomicAdd(&csum[dt], cf);
  int g = inv[dt] >> 8;
  atomicAdd(&QT[s * 4 + g], cf * (1.0f / 256.0f));
}

// ---------------- SpMM (xbar = Ahat @ Xall) + time embedding, merged ----------------
// blocks [0,1024): row h; blocks [1024,1216): time-emb for 2 b's.
__global__ __launch_bounds__(256) void k_spmm(
    const int* __restrict__ row_ptr, const int* __restrict__ csr_src,
    const float* __restrict__ csr_coef, const __hip_bfloat16* __restrict__ Xall,
    __hip_bfloat16* __restrict__ xbar,
    const int* __restrict__ xm, const float* __restrict__ hour_emb,
    const float* __restrict__ wday_emb, const float* __restrict__ twT,
    const float* __restrict__ tcb, float* __restrict__ out) {
  __shared__ float sL[2][512];
  int tid = threadIdx.x, bid = blockIdx.x;
  if (bid < HH) {
    int h = bid;
    int j0 = row_ptr[h], j1 = row_ptr[h + 1];
    float a0 = 0.f, a1 = 0.f, a2 = 0.f, a3 = 0.f, a4 = 0.f, a5 = 0.f;
    for (int j = j0; j < j1; ++j) {
      int s = csr_src[j];
      float cf = csr_coef[j];
      const unsigned* xr = (const unsigned*)(Xall + (size_t)s * 1536);
      unsigned u0 = xr[tid], u1 = xr[tid + 256], u2 = xr[tid + 512];
      union { unsigned i; float f; } lo, hi;
      lo.i = u0 << 16; hi.i = u0 & 0xffff0000u;
      a0 = fmaf(cf, lo.f, a0); a1 = fmaf(cf, hi.f, a1);
      lo.i = u1 << 16; hi.i = u1 & 0xffff0000u;
      a2 = fmaf(cf, lo.f, a2); a3 = fmaf(cf, hi.f, a3);
      lo.i = u2 << 16; hi.i = u2 & 0xffff0000u;
      a4 = fmaf(cf, lo.f, a4); a5 = fmaf(cf, hi.f, a5);
    }
    unsigned* xw = (unsigned*)(xbar + (size_t)h * 1536);
    union { __hip_bfloat16 h2[2]; unsigned u; } pk;
    pk.h2[0] = __float2bfloat16(a0); pk.h2[1] = __float2bfloat16(a1);
    xw[tid] = pk.u;
    pk.h2[0] = __float2bfloat16(a2); pk.h2[1] = __float2bfloat16(a3);
    xw[tid + 256] = pk.u;
    pk.h2[0] = __float2bfloat16(a4); pk.h2[1] = __float2bfloat16(a5);
    xw[tid + 512] = pk.u;
  } else {
    int bb = bid - HH;
    int half = tid >> 7, o = tid & 127;
    int b = bb * 2 + half;
    int n = b / TPP, tp = b % TPP;
    for (int k = 0; k < 4; ++k) {
      int t = tp * 4 + k;
      int wd = xm[(n * TT + t) * 2 + 0];
      int hr = xm[(n * TT + t) * 2 + 1];
      sL[half][o * 4 + k] = hour_emb[hr * DD + o] + wday_emb[wd * DD + o];
    }
    __syncthreads();
    float a0 = tcb[o], a1 = 0.f, a2 = 0.f, a3 = 0.f;
    for (int j = 0; j < 512; j += 4) {
      a0 = fmaf(sL[half][j + 0], twT[(j + 0) * DD + o], a0);
      a1 = fmaf(sL[half][j + 1], twT[(j + 1) * DD + o], a1);
      a2 = fmaf(sL[half][j + 2], twT[(j + 2) * DD + o], a2);
      a3 = fmaf(sL[half][j + 3], twT[(j + 3) * DD + o], a3);
    }
    float acc = (a0 + a1) + (a2 + a3);
    size_t base = (size_t)NOUT + ((size_t)n * TT + tp * 4) * DD + o;
    out[base] = acc;
    out[base + DD] = acc;
    out[base + 2 * DD] = acc;
    out[base + 3 * DD] = acc;
  }
}

// ---------------- k_red: y[b,g,o] = sum_h QT[h,g]*relu(xbar5[b,h,:]@CW + b1) ----------------
// block = (b, quarter): 256 h. Pure VALU, LDS-staged, no atomics.
__global__ __launch_bounds__(256) void k_red(const __hip_bfloat16* __restrict__ xbar,
                                             const float* __restrict__ csum,
                                             const float* __restrict__ QT,
                                             const float* __restrict__ CW,
                                             const float* __restrict__ b1,
                                             float* __restrict__ ypar) {
  __shared__ float4 xb4[256];
  __shared__ float4 qv[256];
  __shared__ float csv[256];
  __shared__ float yL[512];
  int tid = threadIdx.x, bid = blockIdx.x;
  int b = bid >> 2, qt = bid & 3;
  int h = qt * 256 + tid;
  {
    ushort4 us = *(const ushort4*)(xbar + (size_t)h * 1536 + b * 4);
    xb4[tid] = make_float4(us2f(us.x), us2f(us.y), us2f(us.z), us2f(us.w));
    qv[tid] = *(const float4*)(QT + h * 4);
    csv[tid] = csum[h];
  }
  int o = tid & 127, sub = tid >> 7;
  float cw0 = CW[o], cw1 = CW[DD + o], cw2 = CW[2 * DD + o];
  float cw3 = CW[3 * DD + o], cw4 = CW[4 * DD + o];
  float b1o = b1[o];
  __syncthreads();
  float y0 = 0.f, y1 = 0.f, y2 = 0.f, y3 = 0.f;
  int hh0 = sub * 128;
#pragma unroll 4
  for (int hh = hh0; hh < hh0 + 128; ++hh) {
    float4 xv = xb4[hh];
    float4 q = qv[hh];
    float c = csv[hh];
    float t = fmaf(c, cw4, b1o);
    t = fmaf(xv.x, cw0, t);
    t = fmaf(xv.y, cw1, t);
    t = fmaf(xv.z, cw2, t);
    t = fmaf(xv.w, cw3, t);
    t = fmaxf(t, 0.f);
    y0 = fmaf(q.x, t, y0);
    y1 = fmaf(q.y, t, y1);
    y2 = fmaf(q.z, t, y2);
    y3 = fmaf(q.w, t, y3);
  }
  if (sub == 0) {
    yL[o] = y0; yL[DD + o] = y1; yL[2 * DD + o] = y2; yL[3 * DD + o] = y3;
  }
  __syncthreads();
  if (sub == 1) {
    yL[o] += y0; yL[DD + o] += y1; yL[2 * DD + o] += y2; yL[3 * DD + o] += y3;
  }
  __syncthreads();
  float* yp = ypar + ((size_t)qt * BB + b) * 512;
  yp[tid] = yL[tid];
  yp[tid + 256] = yL[tid + 256];
}

// ---------------- epilogue GEMM: out0 = (sum_qt ypar) @ W2 + b2 + time ----------------
__global__ __launch_bounds__(256, 2) void k_out(const float* __restrict__ ypar,
                                                const __hip_bfloat16* __restrict__ w2sw,
                                                const float* __restrict__ b2,
                                                float* __restrict__ out) {
  __shared__ __align__(16) char Wr[32768];
  __shared__ __align__(16) char Gr[16384];
  int tid = threadIdx.x;
  int m0 = blockIdx.x * 64;
  {
    const uint4* ws = (const uint4*)w2sw;
    uint4* wd = (uint4*)Wr;
    for (int i = tid; i < 2048; i += 256) wd[i] = ws[i];
  }
  // A: 64 rows (b,g) x 128 k, fp32 partial-sum -> bf16 pairs, swizzled
#pragma unroll 4
  for (int it = 0; it < 16; ++it) {
    int pi = it * 256 + tid;
    int row = pi >> 6, kp = pi & 63;
    int base = (m0 + row) * 128 + 2 * kp;
    float s0 = 0.f, s1 = 0.f;
#pragma unroll
    for (int p = 0; p < 4; ++p) {
      s0 += ypar[(size_t)p * (BB * 512) + base];
      s1 += ypar[(size_t)p * (BB * 512) + base + 1];
    }
    union { __hip_bfloat16 h[2]; unsigned u; } pk;
    pk.h[0] = __float2bfloat16(s0);
    pk.h[1] = __float2bfloat16(s1);
    *(unsigned*)(Gr + row * 256 + (((kp >> 2) ^ (row & 7)) * 16) + (kp & 3) * 4) = pk.u;
  }
  int lane = tid & 63, w = tid >> 6;
  int colq = lane & 15, quad = lane >> 4;
  float bo[8];
#pragma unroll
  for (int jn = 0; jn < 8; ++jn) bo[jn] = b2[jn * 16 + colq];
  __syncthreads();

  f32x4 acc[8];
#pragma unroll
  for (int jn = 0; jn < 8; ++jn) acc[jn] = (f32x4){0.f, 0.f, 0.f, 0.f};
  int arow = w * 16 + colq;
#pragma unroll
  for (int kc = 0; kc < 4; ++kc) {
    bf16x8 af = *(const bf16x8*)(Gr + arow * 256 + (((kc * 4 + quad) ^ (arow & 7)) * 16));
#pragma unroll
    for (int jn = 0; jn < 8; ++jn) {
      int nr = jn * 16 + colq;
      bf16x8 bf = *(const bf16x8*)(Wr + nr * 256 + (((kc * 4 + quad) ^ (nr & 7)) * 16));
      acc[jn] = __builtin_amdgcn_mfma_f32_16x16x32_bf16(af, bf, acc[jn], 0, 0, 0);
    }
  }
#pragma unroll
  for (int reg = 0; reg < 4; ++reg) {
    int m = m0 + w * 16 + quad * 4 + reg;
    int b = m >> 2, g = m & 3;
    int n_ = b / TPP, tp = b % TPP;
    size_t rb = ((size_t)(n_ * TT + tp * 4 + g)) * DD;
#pragma unroll
    for (int jn = 0; jn < 8; ++jn) {
      int o = jn * 16 + colq;
      out[rb + o] = acc[jn][reg] + bo[jn] + out[(size_t)NOUT + rb + o];
    }
  }
}

extern "C" void kernel_launch(void* const* d_in, const int* in_sizes, int n_in,
                              void* d_out, int out_size, void* d_ws, size_t ws_size,
                              hipStream_t stream) {
  const float* x = (const float*)d_in[0];
  const int* xm = (const int*)d_in[1];
  const int* edges = (const int*)d_in[2];
  const int* node_split = (const int*)d_in[3];
  const float* hour_emb = (const float*)d_in[4];
  const float* wday_emb = (const float*)d_in[5];
  const float* timeconv_w = (const float*)d_in[6];
  const float* timeconv_b = (const float*)d_in[7];
  const float* tcw = (const float*)d_in[8];
  const float* tcb = (const float*)d_in[9];
  const float* W1 = (const float*)d_in[10];
  const float* b1 = (const float*)d_in[11];
  const float* W2 = (const float*)d_in[12];
  const float* b2 = (const float*)d_in[13];
  float* out = (float*)d_out;

  char* w = (char*)d_ws;
  int* degE = (int*)(w + 0);                 //    4096 B (memset)
  int* fill = (int*)(w + 4096);              //    4096 B (zeroed in k_setup)
  float* csum = (float*)(w + 8192);          //    4096 B (zeroed in k_setup)
  float* QT = (float*)(w + 12288);           //   16384 B (zeroed in k_setup)
  int* row_ptr = (int*)(w + 28672);          //    4352 B
  int* inv = (int*)(w + 33024);              //    4096 B
  int* csr_src = (int*)(w + 37120);          //   69632 B
  float* csr_coef = (float*)(w + 106752);    //   69632 B
  __hip_bfloat16* w2sw = (__hip_bfloat16*)(w + 176384);  // 32768 B
  float* CW = (float*)(w + 209152);          //    2560 B (pad to 4096)
  float* twT = (float*)(w + 213248);         //  262144 B
  __hip_bfloat16* Xall = (__hip_bfloat16*)(w + 475392);  // 3145728 B
  float* ypar = (float*)(w + 475392);        // overlay: Xall dead before k_red writes
  __hip_bfloat16* xbar = (__hip_bfloat16*)(w + 3621120); // 3145728 B (end ~6.77 MB)

  hipMemsetAsync(degE, 0, 4096, stream);
  k_setup<<<384, 256, 0, stream>>>(edges, degE, node_split, inv, timeconv_w, twT,
                                   (float*)(w + 4096), x, Xall);
  k_scan<<<1, 1024, 0, stream>>>(degE, row_ptr, tcw, tcb, W1, CW, W2, w2sw);
  k_scatter<<<68, 256, 0, stream>>>(edges, degE, row_ptr, inv, fill, csr_src, csr_coef,
                                    csum, QT);
  k_spmm<<<HH + BB / 2, 256, 0, stream>>>(row_ptr, csr_src, csr_coef, Xall, xbar, xm,
                                          hour_emb, wday_emb, twT, timeconv_b, out);
  k_red<<<BB * 4, 256, 0, stream>>>(xbar, csum, QT, CW, b1, ypar);
  k_out<<<24, 256, 0, stream>>>(ypar, w2sw, b2, out);
}